// Round 6
// baseline (30.279 us; speedup 1.0000x reference)
//
#include <hip/hip_runtime.h>
#include <hip/hip_bf16.h>
#include <math.h>

// TTMultiheadAttention via MFMA (round 5 = round 4 fused into ONE kernel):
//   per s:  G_i[e,d] = sum_q brs_i[e,q] * x[q,s,d]      (mfma 32x32x16 bf16)
//           P_i = exp2(G_i)   (brs pre-scaled by cA2_i*log2e/sqrt(32))
//           OUT_i[b,d] = sum_e CrT[b,e] * P_i[e,d]      (mfma, b row 16 = ones -> l_i)
//           out[b,s,d] = sum_i OUT_i[b,d] / l_i[d]
// Round-5 change: no prep kernel, no d_ws. Each block builds the 40 KB
// weight-fragment set (bf16, prescaled, MFMA A-layout) straight into its own
// LDS from ar/br/cr (L2-resident after first touch). Removes one dependent
// launch from the graph's critical path. Hot loop identical to round 4.

#define SS 512
#define DD 256
#define R2 16
#define NI 3

#define BR_UNITS (NI * 8 * 64)              // 1536 x 16B
#define CR_UNITS (16 * 64)                  // 1024 x 16B
#define ALL_UNITS (BR_UNITS + CR_UNITS)     // 2560 x 16B = 40 KB
#define BR_USH (BR_UNITS * 8)
#define WS_USH (ALL_UNITS * 8)

typedef __attribute__((ext_vector_type(8))) short bf16x8;
typedef __attribute__((ext_vector_type(8))) unsigned short ushort8;
typedef __attribute__((ext_vector_type(4))) float float4v;
typedef __attribute__((ext_vector_type(16))) float f32x16;
typedef __attribute__((ext_vector_type(2))) unsigned uint2v;

union B8 { unsigned w[4]; bf16x8 v; };

static __device__ __forceinline__ unsigned short bf16bits(float f) {
    union { __hip_bfloat16 h; unsigned short u; } c;
    c.h = __float2bfloat16(f);
    return c.u;
}
static __device__ __forceinline__ unsigned packb(float a, float b) {
    union { __hip_bfloat162 h; unsigned u; } c;
    c.h = __float22bfloat162_rn(make_float2(a, b));
    return c.u;
}

__global__ __launch_bounds__(256, 4) void tt_attn_fused(
    const float* __restrict__ x,
    const float* __restrict__ ar,
    const float* __restrict__ br,
    const float* __restrict__ cr,
    float* __restrict__ out)
{
    __shared__ unsigned short lds[WS_USH];   // 40 KB -> 4 blocks/CU

    const int s     = blockIdx.x >> 1;
    const int dhalf = blockIdx.x & 1;
    const int tid   = threadIdx.x;
    const int lane  = tid & 63;
    const int wv    = tid >> 6;
    const int hi    = lane >> 5;
    const int d     = dhalf * 128 + wv * 32 + (lane & 31);

    // Issue x loads first; HBM latency hides under the fragment prep below.
    // lane holds x[q = 8*hi + j][s][d]  (B-operand of stage 1)
    const float* xp = x + s * DD + d + (hi ? 8 * SS * DD : 0);
    float xr[8];
#pragma unroll
    for (int t = 0; t < 8; ++t) xr[t] = xp[t * SS * DD];

    // cA2_i = (sum_k ar[0,k,i]) * log2(e)/sqrt(32)
    float cA2[NI];
#pragma unroll
    for (int i = 0; i < NI; ++i)
        cA2[i] = (ar[i] + ar[NI + i] + ar[2 * NI + i]) *
                 (0.17677669529663687f * 1.4426950408889634f);

    // Build weight fragments in LDS (same layout as rounds 3/4):
    // brf[((i*8+et)*64 + l)*8 + j] = bf16(br[i][et*32+(l&31)][8*(l>>5)+j] * cA2_i)
    // crf[((et*2+h)*64 + l)*8 + j] = b=l&31: b<16 ? cr[b][e] : (b==16 ? 1 : 0),
    //                                e = et*32 + h*16 + 8*(l>>5) + j
#pragma unroll
    for (int c = 0; c < 10; ++c) {
        const int idx = c * 256 + tid;       // 0..2559; branch wave-uniform
        ushort8 v;
        if (idx < BR_UNITS) {
            const int l = idx & 63, et = (idx >> 6) & 7, i = idx >> 9;
            const float* src = br + (i * DD + et * 32 + (l & 31)) * R2 + 8 * (l >> 5);
            const float4v a0 = *(const float4v*)src;
            const float4v a1 = *(const float4v*)(src + 4);
            const float sc = cA2[i];
#pragma unroll
            for (int j = 0; j < 4; ++j) v[j] = bf16bits(a0[j] * sc);
#pragma unroll
            for (int j = 0; j < 4; ++j) v[4 + j] = bf16bits(a1[j] * sc);
        } else {
            const int k = idx - BR_UNITS;    // 0..1023
            const int l = k & 63, h = (k >> 6) & 1, et = k >> 7;
            const int b = l & 31;
#pragma unroll
            for (int j = 0; j < 8; ++j) {
                const int e = et * 32 + h * 16 + 8 * (l >> 5) + j;
                const float val = (b < 16) ? cr[b * DD + e] : (b == 16 ? 1.0f : 0.0f);
                v[j] = bf16bits(val);
            }
        }
        *(ushort8*)(lds + idx * 8) = v;      // ds_write_b128, 16B-aligned
    }

    // pack x fragment while ds_writes drain
    B8 xb;
#pragma unroll
    for (int t = 0; t < 4; ++t) xb.w[t] = packb(xr[2 * t], xr[2 * t + 1]);
    const bf16x8 xf = xb.v;

    __syncthreads();

    f32x16 acc0{}, acc1{}, acc2{};
    const f32x16 zf{};

    const unsigned short* brl = lds + lane * 8;
    const unsigned short* crl = lds + BR_USH + lane * 8;

#pragma unroll 2
    for (int et = 0; et < 8; ++et) {
        const bf16x8 crA0 = *(const bf16x8*)(crl + (et * 2 + 0) * 512);
        const bf16x8 crA1 = *(const bf16x8*)(crl + (et * 2 + 1) * 512);
#pragma unroll
        for (int i = 0; i < NI; ++i) {
            const bf16x8 brA = *(const bf16x8*)(brl + (i * 8 + et) * 512);
            f32x16 g = __builtin_amdgcn_mfma_f32_32x32x16_bf16(brA, xf, zf, 0, 0, 0);
            float p[16];
#pragma unroll
            for (int r = 0; r < 16; ++r) p[r] = __builtin_amdgcn_exp2f(g[r]);
            const unsigned w01 = packb(p[0],  p[1]);
            const unsigned w23 = packb(p[2],  p[3]);
            const unsigned w45 = packb(p[4],  p[5]);
            const unsigned w67 = packb(p[6],  p[7]);
            const unsigned w89 = packb(p[8],  p[9]);
            const unsigned wAB = packb(p[10], p[11]);
            const unsigned wCD = packb(p[12], p[13]);
            const unsigned wEF = packb(p[14], p[15]);
            // lane<->lane+32 half exchange: one swap fills two B-frag words
            const uint2v s0 = __builtin_amdgcn_permlane32_swap(w01, w45, false, false);
            const uint2v s1 = __builtin_amdgcn_permlane32_swap(w23, w67, false, false);
            const uint2v s2 = __builtin_amdgcn_permlane32_swap(w89, wCD, false, false);
            const uint2v s3 = __builtin_amdgcn_permlane32_swap(wAB, wEF, false, false);
            B8 P0; P0.w[0] = s0.x; P0.w[1] = s1.x; P0.w[2] = s0.y; P0.w[3] = s1.y;
            B8 P1; P1.w[0] = s2.x; P1.w[1] = s3.x; P1.w[2] = s2.y; P1.w[3] = s3.y;
            if (i == 0) {
                acc0 = __builtin_amdgcn_mfma_f32_32x32x16_bf16(crA0, P0.v, acc0, 0, 0, 0);
                acc0 = __builtin_amdgcn_mfma_f32_32x32x16_bf16(crA1, P1.v, acc0, 0, 0, 0);
            } else if (i == 1) {
                acc1 = __builtin_amdgcn_mfma_f32_32x32x16_bf16(crA0, P0.v, acc1, 0, 0, 0);
                acc1 = __builtin_amdgcn_mfma_f32_32x32x16_bf16(crA1, P1.v, acc1, 0, 0, 0);
            } else {
                acc2 = __builtin_amdgcn_mfma_f32_32x32x16_bf16(crA0, P0.v, acc2, 0, 0, 0);
                acc2 = __builtin_amdgcn_mfma_f32_32x32x16_bf16(crA1, P1.v, acc2, 0, 0, 0);
            }
        }
    }

    // l_i sits in C row 16 = reg 8 of hi=0 lanes; broadcast to hi=1 half
    float inv[NI];
#pragma unroll
    for (int i = 0; i < NI; ++i) {
        union { float f; unsigned u; } c;
        c.f = (i == 0) ? acc0[8] : (i == 1) ? acc1[8] : acc2[8];
        const uint2v r = __builtin_amdgcn_permlane32_swap(c.u, c.u, false, false);
        union { unsigned u; float f; } c2; c2.u = r.x;
        inv[i] = 1.0f / c2.f;
    }

#pragma unroll
    for (int r = 0; r < 8; ++r) {
        const int b = (r & 3) + 8 * (r >> 2) + 4 * hi;
        const float o = acc0[r] * inv[0] + acc1[r] * inv[1] + acc2[r] * inv[2];
        out[(b * SS + s) * DD + d] = o;
    }
}

extern "C" void kernel_launch(void* const* d_in, const int* in_sizes, int n_in,
                              void* d_out, int out_size, void* d_ws, size_t ws_size,
                              hipStream_t stream) {
    const float* x  = (const float*)d_in[0];
    const float* ar = (const float*)d_in[1];
    const float* br = (const float*)d_in[2];
    const float* cr = (const float*)d_in[3];
    float* out = (float*)d_out;

    hipLaunchKernelGGL(tt_attn_fused, dim3(SS * 2), dim3(256), 0, stream,
                       x, ar, br, cr, out);
}

// Round 7
// 28.345 us; speedup vs baseline: 1.0682x; 1.0682x over previous
//
#include <hip/hip_runtime.h>
#include <hip/hip_bf16.h>
#include <math.h>

// TTMultiheadAttention via MFMA (round 6 = round 4 + rank-split across waves):
//   per s:  G_i[e,d] = sum_q brs_i[e,q] * x[q,s,d]      (mfma 32x32x16 bf16)
//           P_i = exp2(G_i)   (brs pre-scaled by cA2_i*log2e/sqrt(32))
//           OUT_i[b,d] = sum_e CrT[b,e] * P_i[e,d]      (mfma, b row 16 = ones -> l_i)
//           out[b,s,d] = sum_i OUT_i[b,d] / l_i[d]
// Round-6 change: block = (256,3) = 12 waves; wave (wv,i) computes ONE rank i
// for its 32-wide d tile. Per-wave VGPR drops to ~70 (acc 16 instead of 48),
// launch_bounds(768,6) -> 24 waves/CU (75% occupancy, was 50%), 3x shorter
// dependency chains. Rank partials (already 1/l_i-scaled) merge via 16 KB LDS.
// Two-kernel structure (prep into d_ws + global_load_lds staging) per round-4.

#define SS 512
#define DD 256
#define R2 16
#define NI 3

#define BR_UNITS (NI * 8 * 64)              // 1536 x 16B
#define CR_UNITS (16 * 64)                  // 1024 x 16B
#define ALL_UNITS (BR_UNITS + CR_UNITS)     // 2560 x 16B = 40 KB
#define BR_USH (BR_UNITS * 8)               // 12288 ushorts
#define WS_USH (ALL_UNITS * 8)              // 20480 ushorts

typedef __attribute__((ext_vector_type(8))) short bf16x8;
typedef __attribute__((ext_vector_type(8))) unsigned short ushort8;
typedef __attribute__((ext_vector_type(16))) float f32x16;
typedef __attribute__((ext_vector_type(4))) float float4v;
typedef __attribute__((ext_vector_type(2))) unsigned uint2v;

union B8 { unsigned w[4]; bf16x8 v; };

static __device__ __forceinline__ unsigned short bf16bits(float f) {
    union { __hip_bfloat16 h; unsigned short u; } c;
    c.h = __float2bfloat16(f);
    return c.u;
}
static __device__ __forceinline__ unsigned packb(float a, float b) {
    union { __hip_bfloat162 h; unsigned u; } c;
    c.h = __float22bfloat162_rn(make_float2(a, b));
    return c.u;
}

// Fragment packing (one b128 store per thread, 2560 threads = grid 10 x 256):
// brf[((i*8+et)*64 + l)*8 + j] = bf16(br[i][et*32+(l&31)][8*(l>>5)+j] * cA2_i)
// crf[((et*2+h)*64 + l)*8 + j] = b=l&31: b<16 ? cr[b][e] : (b==16 ? 1 : 0),
//                                e = et*32 + h*16 + 8*(l>>5) + j
__global__ void tt_prep(const float* __restrict__ ar,
                        const float* __restrict__ br,
                        const float* __restrict__ cr,
                        unsigned short* __restrict__ wsf)
{
    const int t = blockIdx.x * 256 + threadIdx.x;   // 0..2559
    float cA2[NI];
#pragma unroll
    for (int i = 0; i < NI; ++i) {
        float A = ar[0 * NI + i] + ar[1 * NI + i] + ar[2 * NI + i];
        cA2[i] = A * (0.17677669529663687f * 1.4426950408889634f);
    }
    if (t < BR_UNITS) {
        const int l = t & 63, et = (t >> 6) & 7, i = t >> 9;
        const float* src = br + (i * DD + et * 32 + (l & 31)) * R2 + 8 * (l >> 5);
        const float sc = cA2[i];
        ushort8 v;
#pragma unroll
        for (int j = 0; j < 8; ++j) v[j] = bf16bits(src[j] * sc);
        *(ushort8*)(wsf + t * 8) = v;
    } else {
        const int idx = t - BR_UNITS;               // 0..1023
        const int l = idx & 63, h = (idx >> 6) & 1, et = idx >> 7;
        const int b = l & 31;
        ushort8 v;
#pragma unroll
        for (int j = 0; j < 8; ++j) {
            const int e = et * 32 + h * 16 + 8 * (l >> 5) + j;
            float val = (b < 16) ? cr[b * DD + e] : (b == 16 ? 1.0f : 0.0f);
            v[j] = bf16bits(val);
        }
        *(ushort8*)(wsf + (BR_USH + idx * 8)) = v;
    }
}

__global__ __launch_bounds__(768, 6) void tt_attn_mfma(
    const float* __restrict__ x,
    const unsigned short* __restrict__ wsf,
    float* __restrict__ out)
{
    __shared__ unsigned short lds_w[WS_USH];        // 40 KB weight fragments
    __shared__ float lds_p[2][4][64][8];            // 16 KB rank partials

    const int s     = blockIdx.x >> 1;
    const int dhalf = blockIdx.x & 1;
    const int tx    = threadIdx.x;                  // 0..255
    const int i     = threadIdx.y;                  // 0..2 rank, wave-uniform
    const int lane  = tx & 63;
    const int wv    = tx >> 6;                      // d-tile 0..3
    const int hi    = lane >> 5;
    const int d     = dhalf * 128 + wv * 32 + (lane & 31);
    const int ft    = i * 256 + tx;                 // flat 0..767

    // Stage all weight fragments to LDS: 2560 x 16B across 768 threads.
#pragma unroll
    for (int c = 0; c < 4; ++c) {
        const int idx = c * 768 + ft;               // wave-uniform predicate
        if (idx < ALL_UNITS) {
            const char* g = (const char*)wsf + (size_t)idx * 16;
            char* lp = (char*)lds_w + (size_t)(idx - lane) * 16;  // wave-uniform base
            __builtin_amdgcn_global_load_lds(
                (const __attribute__((address_space(1))) void*)g,
                (__attribute__((address_space(3))) void*)lp, 16, 0, 0);
        }
    }

    // x fragment (issues while LDS staging is in flight):
    // lane holds x[q = 8*hi + j][s][d]  (B-operand of stage 1)
    const float* xp = x + s * DD + d + (hi ? 8 * SS * DD : 0);
    float xr[8];
#pragma unroll
    for (int t = 0; t < 8; ++t) xr[t] = xp[t * SS * DD];
    B8 xb;
#pragma unroll
    for (int t = 0; t < 4; ++t) xb.w[t] = packb(xr[2 * t], xr[2 * t + 1]);
    const bf16x8 xf = xb.v;

    __syncthreads();   // drains vmcnt (global_load_lds) per compiler semantics

    f32x16 acc{};
    const f32x16 zf{};

    const unsigned short* brl = lds_w + lane * 8;
    const unsigned short* crl = lds_w + BR_USH + lane * 8;

#pragma unroll 2
    for (int et = 0; et < 8; ++et) {
        const bf16x8 crA0 = *(const bf16x8*)(crl + (et * 2 + 0) * 512);
        const bf16x8 crA1 = *(const bf16x8*)(crl + (et * 2 + 1) * 512);
        const bf16x8 brA  = *(const bf16x8*)(brl + (i * 8 + et) * 512);
        f32x16 g = __builtin_amdgcn_mfma_f32_32x32x16_bf16(brA, xf, zf, 0, 0, 0);
        float p[16];
#pragma unroll
        for (int r = 0; r < 16; ++r) p[r] = __builtin_amdgcn_exp2f(g[r]);
        const unsigned w01 = packb(p[0],  p[1]);
        const unsigned w23 = packb(p[2],  p[3]);
        const unsigned w45 = packb(p[4],  p[5]);
        const unsigned w67 = packb(p[6],  p[7]);
        const unsigned w89 = packb(p[8],  p[9]);
        const unsigned wAB = packb(p[10], p[11]);
        const unsigned wCD = packb(p[12], p[13]);
        const unsigned wEF = packb(p[14], p[15]);
        // lane<->lane+32 half exchange: one swap fills two B-frag words
        const uint2v s0 = __builtin_amdgcn_permlane32_swap(w01, w45, false, false);
        const uint2v s1 = __builtin_amdgcn_permlane32_swap(w23, w67, false, false);
        const uint2v s2 = __builtin_amdgcn_permlane32_swap(w89, wCD, false, false);
        const uint2v s3 = __builtin_amdgcn_permlane32_swap(wAB, wEF, false, false);
        B8 P0; P0.w[0] = s0.x; P0.w[1] = s1.x; P0.w[2] = s0.y; P0.w[3] = s1.y;
        B8 P1; P1.w[0] = s2.x; P1.w[1] = s3.x; P1.w[2] = s2.y; P1.w[3] = s3.y;
        acc = __builtin_amdgcn_mfma_f32_32x32x16_bf16(crA0, P0.v, acc, 0, 0, 0);
        acc = __builtin_amdgcn_mfma_f32_32x32x16_bf16(crA1, P1.v, acc, 0, 0, 0);
    }

    // l_i sits in C row 16 = reg 8 of hi=0 lanes; broadcast to hi=1 half
    float inv;
    {
        union { float f; unsigned u; } c;
        c.f = acc[8];
        const uint2v r = __builtin_amdgcn_permlane32_swap(c.u, c.u, false, false);
        union { unsigned u; float f; } c2; c2.u = r.x;
        inv = 1.0f / c2.f;
    }

    float sc[8];
#pragma unroll
    for (int r = 0; r < 8; ++r) sc[r] = acc[r] * inv;

    if (i > 0) {
        float* pp = &lds_p[i - 1][wv][lane][0];
        *(float4v*)pp       = *(const float4v*)&sc[0];   // ds_write_b128
        *(float4v*)(pp + 4) = *(const float4v*)&sc[4];
    }
    __syncthreads();

    if (i == 0) {
        const float* p1 = &lds_p[0][wv][lane][0];
        const float* p2 = &lds_p[1][wv][lane][0];
#pragma unroll
        for (int r = 0; r < 8; ++r) {
            const int b = (r & 3) + 8 * (r >> 2) + 4 * hi;
            out[(b * SS + s) * DD + d] = sc[r] + p1[r] + p2[r];
        }
    }
}

extern "C" void kernel_launch(void* const* d_in, const int* in_sizes, int n_in,
                              void* d_out, int out_size, void* d_ws, size_t ws_size,
                              hipStream_t stream) {
    const float* x  = (const float*)d_in[0];
    const float* ar = (const float*)d_in[1];
    const float* br = (const float*)d_in[2];
    const float* cr = (const float*)d_in[3];
    float* out = (float*)d_out;

    unsigned short* wsf = (unsigned short*)d_ws;   // 40 KB: brf (24K) then crf (16K)

    hipLaunchKernelGGL(tt_prep, dim3(10), dim3(256), 0, stream, ar, br, cr, wsf);
    hipLaunchKernelGGL(tt_attn_mfma, dim3(SS * 2), dim3(256, NI), 0, stream,
                       x, wsf, out);
}